// Round 17
// baseline (574.682 us; speedup 1.0000x reference)
//
#include <hip/hip_runtime.h>
#include <hip/hip_bf16.h>
#include <math.h>

#define NGRAPH 128
#define NPG_   512
#define NN     (NGRAPH*NPG_)     // 65536 nodes
#define EPG    504
#define ETOT   (NGRAPH*EPG)      // 64512 real edges
#define HEADS  8
#define FDIM   512
#define NEG    0.2f

typedef __hip_bfloat16 bf16;
typedef __attribute__((ext_vector_type(8))) short short8;   // 8 bf16 = 4 VGPR
typedef __attribute__((ext_vector_type(4))) float f32x4;

static __device__ __forceinline__ float bf(short s){
  union { unsigned u; float f; } c; c.u = ((unsigned)(unsigned short)s) << 16; return c.f;
}
static __device__ __forceinline__ short fbf(float v){
  bf16 b = __float2bfloat16(v); return *(short*)&b;
}

static __device__ __forceinline__ void gload16(void* lds, const void* g){
  __builtin_amdgcn_global_load_lds((const __attribute__((address_space(1))) void*)g,
                                   (__attribute__((address_space(3))) void*)lds, 16, 0, 0);
}

// ---------------- workspace guard ----------------
__global__ void k_sentinel(float* out, int n){
  int i = blockIdx.x*blockDim.x + threadIdx.x;
  if (i < n) out[i] = 12345.0f;
}

// ---- one kernel: CSR build (0..127) + coef (128..130) + layer1 ws/wd (131) + wt (132..1155) ----
__global__ __launch_bounds__(512) void k_csr(const int* __restrict__ ei, const float* __restrict__ ea,
                                             const float* __restrict__ We0, const float* __restrict__ ae0,
                                             const float* __restrict__ We1, const float* __restrict__ ae1,
                                             const float* __restrict__ We2, const float* __restrict__ ae2,
                                             const float* __restrict__ W1,
                                             const float* __restrict__ as1, const float* __restrict__ ad1,
                                             const float* __restrict__ Wl2, const float* __restrict__ Wl3,
                                             int* __restrict__ deg_g, int* __restrict__ row_ptr,
                                             float* __restrict__ la,
                                             int* __restrict__ esrc, float* __restrict__ eattr,
                                             float* __restrict__ coef, float* __restrict__ wsd,
                                             bf16* __restrict__ wt){
  int b = blockIdx.x;
  int t = threadIdx.x;
  if (b >= NGRAPH){
    if (b < NGRAPH+3){                  // coef[l][h] = sum_c We[h*64+c]*ae[h*64+c]
      int l = b - NGRAPH;
      const float* We = l==0 ? We0 : (l==1 ? We1 : We2);
      const float* ae = l==0 ? ae0 : (l==1 ? ae1 : ae2);
      float v = We[t]*ae[t];
      #pragma unroll
      for (int o=32;o>0;o>>=1) v += __shfl_down(v, o);
      if ((t & 63) == 0) coef[l*HEADS + (t>>6)] = v;
      return;
    }
    if (b == NGRAPH+3){
      // layer-1 x-space attention vectors: ws[h][k] = sum_c W1[k*512+h*64+c]*as1[h*64+c]
      float as_v = as1[t], ad_v = ad1[t];
      float v[6] = { W1[t]*as_v, W1[512+t]*as_v, W1[1024+t]*as_v,
                     W1[t]*ad_v, W1[512+t]*ad_v, W1[1024+t]*ad_v };
      #pragma unroll
      for (int o=32;o>0;o>>=1){
        #pragma unroll
        for (int q=0;q<6;q++) v[q] += __shfl_down(v[q], o);
      }
      if ((t & 63) == 0){
        int w = t >> 6;
        wsd[w*3+0]    = v[0]; wsd[w*3+1]    = v[1]; wsd[w*3+2]    = v[2];
        wsd[24+w*3+0] = v[3]; wsd[24+w*3+1] = v[4]; wsd[24+w*3+2] = v[5];
      }
      return;
    }
    // wt blocks: transpose W2/W3 to bf16 [n][k]
    int idx = (b - (NGRAPH+4))*512 + t;          // [0, 2*FDIM*FDIM)
    int l = idx >> 18;
    int r = idx & (FDIM*FDIM-1);
    int n = r >> 9, k = r & 511;
    const float* W = l ? Wl3 : Wl2;
    wt[idx] = __float2bfloat16(W[k*FDIM + n]);
    return;
  }
  __shared__ int   dg[512];
  __shared__ float ss[512];
  __shared__ int   scan[512];
  __shared__ int   cur[512];
  dg[t] = 0; ss[t] = 0.f;
  __syncthreads();
  int src=0, dst=0; float at=0.f;
  if (t < EPG){
    src = ei[(b*EPG+t)*2];
    dst = ei[(b*EPG+t)*2+1];
    at  = ea[b*EPG+t];
    atomicAdd(&dg[dst], 1);
    atomicAdd(&ss[dst], at);
  }
  __syncthreads();
  int d = dg[t];
  scan[t] = d;
  __syncthreads();
  for (int o=1;o<512;o<<=1){
    int v2 = (t>=o) ? scan[t-o] : 0;
    __syncthreads();
    scan[t] += v2;
    __syncthreads();
  }
  int excl = scan[t] - d;
  int n = b*NPG_ + t;
  row_ptr[n] = b*EPG + excl;
  deg_g[n]   = d;
  la[n]      = ss[t] / fmaxf((float)d, 1.f);
  cur[t] = excl;
  __syncthreads();
  if (t < EPG){
    int slot = atomicAdd(&cur[dst], 1);
    int p = b*EPG + slot;
    esrc[p]  = b*NPG_ + src;
    eattr[p] = at;
  }
}

// ---------------- fully-fused layer 1 in x-space (3-dim) ----------------
__global__ __launch_bounds__(256) void k_gat1(const float* __restrict__ x,
                                              const float* __restrict__ W,
                                              const float* __restrict__ wsd,
                                              const float* __restrict__ coef,
                                              const int* __restrict__ row_ptr,
                                              const int* __restrict__ deg,
                                              const int* __restrict__ esrc,
                                              const float* __restrict__ eattr,
                                              const float* __restrict__ bias,
                                              bf16* __restrict__ h){
  int nwg = gridDim.x;                   // 16384, %8 == 0
  int cpx = nwg >> 3;
  int bid = blockIdx.x;
  int swz = (bid & 7)*cpx + (bid >> 3);
  int n = swz*4 + (threadIdx.x >> 6);
  int lane = threadIdx.x & 63;
  int hh = lane >> 3;
  int f0 = lane << 3;

  float ws0 = wsd[hh*3+0],    ws1 = wsd[hh*3+1],    ws2 = wsd[hh*3+2];
  float wd0 = wsd[24+hh*3+0], wd1 = wsd[24+hh*3+1], wd2 = wsd[24+hh*3+2];
  float ch = coef[hh];

  const float* xr = x + n*3;
  float aldn = xr[0]*wd0 + xr[1]*wd1 + xr[2]*wd2;

  int row = row_ptr[n], d = deg[n];
  float m = -1e30f, ssum = 0.f;
  float a0 = 0.f, a1 = 0.f, a2 = 0.f;
  for (int i=0;i<d;i++){
    int s = esrc[row+i]; float at = eattr[row+i];
    const float* xsr = x + s*3;
    float y0 = xsr[0], y1 = xsr[1], y2 = xsr[2];
    float raw = y0*ws0 + y1*ws1 + y2*ws2 + aldn + at*ch;
    raw = raw > 0.f ? raw : NEG*raw;
    float mn = fmaxf(m, raw);
    float sc = __expf(m - mn);
    float p  = __expf(raw - mn);
    ssum = ssum*sc + p;
    a0 = a0*sc + p*y0;
    a1 = a1*sc + p*y1;
    a2 = a2*sc + p*y2;
    m = mn;
  }
  float inv = 1.f / fmaxf(ssum, 1e-16f);
  a0 *= inv; a1 *= inv; a2 *= inv;

  float w0[8], w1[8], w2[8], b8[8];
  #pragma unroll
  for (int j=0;j<8;j+=4){
    *(float4*)&w0[j] = *(const float4*)&W[f0+j];
    *(float4*)&w1[j] = *(const float4*)&W[FDIM+f0+j];
    *(float4*)&w2[j] = *(const float4*)&W[2*FDIM+f0+j];
    *(float4*)&b8[j] = *(const float4*)&bias[f0+j];
  }
  short8 r;
  #pragma unroll
  for (int j=0;j<8;j++){
    float o = a0*w0[j] + a1*w1[j] + a2*w2[j] + b8[j];
    r[j] = fbf(o > 0.f ? o : 0.f);
  }
  ((short8*)(h + (size_t)n*FDIM))[lane] = r;
}

// ---------------- fused GAT: single-pass online softmax; wave per node ----------------
__global__ __launch_bounds__(256) void k_gat(const bf16* __restrict__ xs,
                                             const float* __restrict__ als,
                                             const float* __restrict__ ald,
                                             const float* __restrict__ coef,
                                             const int* __restrict__ row_ptr,
                                             const int* __restrict__ deg,
                                             const int* __restrict__ esrc,
                                             const float* __restrict__ eattr,
                                             const float* __restrict__ la,
                                             const float* __restrict__ bias,
                                             bf16* __restrict__ h){
  int nwg = gridDim.x;                   // 16384, %8 == 0
  int cpx = nwg >> 3;
  int bid = blockIdx.x;
  int swz = (bid & 7)*cpx + (bid >> 3);
  int n = swz*4 + (threadIdx.x >> 6);
  int lane = threadIdx.x & 63;
  int hh = lane >> 3;                    // head of my 8 features
  int row = row_ptr[n], d = deg[n];
  int tot = d + 1;                       // self loop
  float aldn = ald[n*HEADS+hh];
  float ch = coef[hh];
  float lan = la[n];

  float m = -1e30f, ssum = 0.f;
  float acc[8] = {};
  for (int i=0;i<tot;i++){
    int s; float at;
    if (i<d){ s = esrc[row+i]; at = eattr[row+i]; }
    else    { s = n;           at = lan; }
    float raw = als[s*HEADS+hh] + aldn + at*ch;
    raw = raw > 0.f ? raw : NEG*raw;
    float mn = fmaxf(m, raw);
    float scale = __expf(m - mn);        // 1 if max unchanged; 0 on first iter
    float p = __expf(raw - mn);
    ssum = ssum*scale + p;
    short8 v = ((const short8*)(xs + (size_t)s*FDIM))[lane];
    #pragma unroll
    for (int j=0;j<8;j++) acc[j] = acc[j]*scale + p*bf(v[j]);
    m = mn;
  }
  float inv = 1.f / fmaxf(ssum, 1e-16f);
  const float4* b4 = (const float4*)bias;
  float4 ba = b4[lane*2], bb = b4[lane*2+1];
  float bias8[8] = {ba.x,ba.y,ba.z,ba.w,bb.x,bb.y,bb.z,bb.w};
  short8 r;
  #pragma unroll
  for (int j=0;j<8;j++){
    float o = acc[j]*inv + bias8[j];
    r[j] = fbf(o > 0.f ? o : 0.f);
  }
  ((short8*)(h + (size_t)n*FDIM))[lane] = r;
}

// ------- 256x256 MFMA GEMM, BK=32: 2-slot 64KB pipeline -> 2 blocks/CU -------
// Occupancy was the r14-r16 stall: 128KB LDS = 1 block/CU = 2 waves/SIMD, nothing to
// run during barrier/vmcnt waits. BK=32 halves the slot (A16K+B16K), 2 slots = 64KB
// -> 2 blocks/CU (4 waves/SIMD) of cross-block overlap (m114). Counted vmcnt(4).
// Row = 4 granules; swizzle g^((row>>1)&3): bank = 16(row&1)+4swz -> 2-way free.
__global__ __launch_bounds__(512, 4) void gemm_mfma(const bf16* __restrict__ A,
                                                    const bf16* __restrict__ Wt,
                                                    const float* __restrict__ a_s,
                                                    const float* __restrict__ a_d,
                                                    bf16* __restrict__ C,
                                                    float* __restrict__ als,
                                                    float* __restrict__ ald,
                                                    int M, int N, int K){
  extern __shared__ short smem[];        // 2 slots * 16384 shorts (A 8192 + B 8192)
  int bid = blockIdx.x;
  int wk = ((bid & 7) << 6) | (bid >> 3);    // XCD chunk swizzle (512 = 8*64)
  const int bm = (wk >> 1)*256, bn = (wk & 1)*256;   // N-minor: A-panel L2 reuse
  const int tid = threadIdx.x;
  const int lane = tid & 63;
  const int w = tid >> 6;                // 0..7
  const int wm = (w >> 2)*128;           // 0,128
  const int wn = (w & 3)*64;             // 0,64,128,192
  const int lr = lane & 15;
  const int lk = lane >> 4;              // granule 0..3

  f32x4 acc[8][4] = {};
  const int nt = K >> 5;                 // 16 K-tiles of 32

  // STAGE tile t into slot s: 4 gload16/thread (2 A + 2 B), linear dest, swizzled src
  auto STAGE = [&](int s, int t){
    short* Al = smem + s*16384;
    short* Bl = smem + s*16384 + 8192;
    int k0 = t << 5;
    #pragma unroll
    for (int ph=0; ph<2; ++ph){
      int i = ph*512 + tid;              // 0..1023 granules (256 rows x 4)
      int r = i >> 2, g = i & 3;
      int gs = g ^ ((r >> 1) & 3);       // inverse swizzle on source
      gload16(&Al[i*8], A  + (size_t)(bm+r)*K + k0 + gs*8);
      gload16(&Bl[i*8], Wt + (size_t)(bn+r)*K + k0 + gs*8);
    }
  };

  STAGE(0, 0);
  for (int t = 0; t < nt; ++t){
    int s = t & 1;
    if (t+1 < nt){
      STAGE(s^1, t+1);
      asm volatile("s_waitcnt vmcnt(4)" ::: "memory");   // tile t landed; t+1 in flight
    } else {
      asm volatile("s_waitcnt vmcnt(0)" ::: "memory");   // last tile: drain
    }
    __builtin_amdgcn_s_barrier();
    const short* Al = smem + s*16384;
    const short* Bl = smem + s*16384 + 8192;
    __builtin_amdgcn_s_setprio(1);
    {
      short8 af[8], bfr[4];
      #pragma unroll
      for (int mi=0; mi<8; ++mi){
        int row = wm + mi*16 + lr;
        af[mi] = *(const short8*)&Al[row*32 + ((lk ^ ((row>>1)&3)))*8];
      }
      #pragma unroll
      for (int ni=0; ni<4; ++ni){
        int row = wn + ni*16 + lr;
        bfr[ni] = *(const short8*)&Bl[row*32 + ((lk ^ ((row>>1)&3)))*8];
      }
      #pragma unroll
      for (int mi=0; mi<8; ++mi)
        #pragma unroll
        for (int ni=0; ni<4; ++ni)
          acc[mi][ni] = __builtin_amdgcn_mfma_f32_16x16x32_bf16(af[mi], bfr[ni], acc[mi][ni], 0,0,0);
    }
    __builtin_amdgcn_s_setprio(0);
    __builtin_amdgcn_s_barrier();        // all frags consumed -> restage-safe next iter
  }

  // fused attention logits from hot f32 acc: this wave's 64 cols = one head
  int hh = (bn + wn) >> 6;
  float as_c[4], ad_c[4];
  #pragma unroll
  for (int ni=0; ni<4; ++ni){
    int c = bn + wn + ni*16 + lr;       // == hh*64 + ni*16 + lr
    as_c[ni] = a_s[c & 511];
    ad_c[ni] = a_d[c & 511];
  }
  #pragma unroll
  for (int mi=0; mi<8; ++mi)
    #pragma unroll
    for (int r=0; r<4; ++r){
      float s = acc[mi][0][r]*as_c[0] + acc[mi][1][r]*as_c[1]
              + acc[mi][2][r]*as_c[2] + acc[mi][3][r]*as_c[3];
      float d = acc[mi][0][r]*ad_c[0] + acc[mi][1][r]*ad_c[1]
              + acc[mi][2][r]*ad_c[2] + acc[mi][3][r]*ad_c[3];
      #pragma unroll
      for (int o=1;o<16;o<<=1){ s += __shfl_xor(s, o); d += __shfl_xor(d, o); }
      if (lr == 0){
        int rowg = bm + wm + mi*16 + lk*4 + r;
        als[rowg*HEADS+hh] = s;
        ald[rowg*HEADS+hh] = d;
      }
    }

  // C write: col = lane&15, row = (lane>>4)*4 + reg   (m89 layout)
  #pragma unroll
  for (int mi=0; mi<8; ++mi)
    #pragma unroll
    for (int ni=0; ni<4; ++ni){
      int col = bn + wn + ni*16 + lr;
      #pragma unroll
      for (int r=0; r<4; ++r){
        int rowg = bm + wm + mi*16 + lk*4 + r;
        C[(size_t)rowg*N + col] = __float2bfloat16(acc[mi][ni][r]);
      }
    }
}

// ---- head part 1: FC1 partials, K-split 8x; graph-mean chunk computed in-kernel ----
__global__ __launch_bounds__(256) void k_head1(const bf16* __restrict__ h,
                                               const float* __restrict__ fc1w,
                                               float* __restrict__ pf1,
                                               float* __restrict__ pge){
  __shared__ float geP[4][64];
  __shared__ float ge[64];
  __shared__ float ag[8][64];
  int blk = blockIdx.x;                 // g*8 + q
  int g = blk >> 3, q = blk & 7;
  int t = threadIdx.x;
  int k0 = q*64;

  // graph-mean partial for this 64-chunk: 4 row-groups x 128 rows, coalesced 128B rows
  {
    int cg = t & 63, rg = t >> 6;
    const bf16* p = h + ((size_t)(g*NPG_ + rg*128))*FDIM + k0 + cg;
    float s = 0.f;
    #pragma unroll 8
    for (int r=0;r<128;r++) s += bf(*(const short*)(p + (size_t)r*FDIM));
    geP[rg][cg] = s;
  }
  // agent rows (first 8 nodes of graph): 64 units = 8 rows x 8 short8
  if (t < 64){
    int r = t >> 3, c8 = t & 7;
    short8 v = ((const short8*)(h + ((size_t)(g*NPG_ + r))*FDIM + k0))[c8];
    #pragma unroll
    for (int j=0;j<8;j++) ag[r][c8*8+j] = bf(v[j]);
  }
  __syncthreads();
  if (t < 64) ge[t] = (geP[0][t]+geP[1][t]+geP[2][t]+geP[3][t]) * (1.f/NPG_);
  __syncthreads();

  float acc[8] = {};
  float gacc = 0.f;
  for (int kk=0; kk<64; kk++){
    float wa = fc1w[(size_t)(k0+kk)*256 + t];
    float wg = fc1w[(size_t)(FDIM+k0+kk)*256 + t];
    #pragma unroll
    for (int r=0;r<8;r++) acc[r] += ag[r][kk]*wa;
    gacc += ge[kk]*wg;
  }
  #pragma unroll
  for (int r=0;r<8;r++) pf1[((size_t)q*1024 + g*8 + r)*256 + t] = acc[r];
  pge[((size_t)q*NGRAPH + g)*256 + t] = gacc;
}

// ---------------- head part 2: reduce partials + bias + ReLU + FC2 ----------------
__global__ __launch_bounds__(256) void k_fc2(const float* __restrict__ pf1,
                                             const float* __restrict__ pge,
                                             const float* __restrict__ fc1b,
                                             const float* __restrict__ fc2w,
                                             const float* __restrict__ fc2b,
                                             float* __restrict__ out){
  __shared__ float f1[8][256];
  int g = blockIdx.x, t = threadIdx.x;
  float ges = 0.f;
  #pragma unroll
  for (int q=0;q<8;q++) ges += pge[((size_t)q*NGRAPH + g)*256 + t];
  float b = fc1b[t] + ges;
  #pragma unroll
  for (int r=0;r<8;r++){
    float s = 0.f;
    #pragma unroll
    for (int q=0;q<8;q++) s += pf1[((size_t)q*1024 + g*8 + r)*256 + t];
    f1[r][t] = fmaxf(s + b, 0.f);
  }
  __syncthreads();
  if (t < 128){
    int r = t >> 4, o = (t >> 3) & 1, l = t & 7;
    float s = 0.f;
    for (int k = l; k < 256; k += 8) s += f1[r][k] * fc2w[k*2+o];
    #pragma unroll
    for (int off=4; off; off>>=1) s += __shfl_down(s, off);
    if (l == 0) out[(g*8 + r)*2 + o] = s + fc2b[o];
  }
}

extern "C" void kernel_launch(void* const* d_in, const int* in_sizes, int n_in,
                              void* d_out, int out_size, void* d_ws, size_t ws_size,
                              hipStream_t stream)
{
  const float* x    = (const float*)d_in[0];
  const int*   ei   = (const int*)  d_in[1];
  const float* ea   = (const float*)d_in[2];
  const float* Wl[3]  = {(const float*)d_in[3],  (const float*)d_in[9],  (const float*)d_in[15]};
  const float* Bl[3]  = {(const float*)d_in[4],  (const float*)d_in[10], (const float*)d_in[16]};
  const float* ASl[3] = {(const float*)d_in[5],  (const float*)d_in[11], (const float*)d_in[17]};
  const float* ADl[3] = {(const float*)d_in[6],  (const float*)d_in[12], (const float*)d_in[18]};
  const float* WEl[3] = {(const float*)d_in[7],  (const float*)d_in[13], (const float*)d_in[19]};
  const float* AEl[3] = {(const float*)d_in[8],  (const float*)d_in[14], (const float*)d_in[20]};
  const float* FC1W = (const float*)d_in[21];
  const float* FC1B = (const float*)d_in[22];
  const float* FC2W = (const float*)d_in[23];
  const float* FC2B = (const float*)d_in[24];
  float* out = (float*)d_out;
  (void)in_sizes; (void)n_in;

  char* ws = (char*)d_ws;
  size_t off = 0;
  auto alloc = [&](size_t bytes)->char*{
    char* p = ws + off;
    off = (off + bytes + 255) & ~(size_t)255;
    return p;
  };
  bf16*  h       = (bf16*) alloc((size_t)NN*FDIM*2);    // 64 MB
  bf16*  xs      = (bf16*) alloc((size_t)NN*FDIM*2);    // 64 MB
  float* als     = (float*)alloc((size_t)NN*HEADS*4);   // 2 MB
  float* ald     = (float*)alloc((size_t)NN*HEADS*4);   // 2 MB
  float* la      = (float*)alloc((size_t)NN*4);
  int*   deg     = (int*)  alloc((size_t)NN*4);
  int*   row_ptr = (int*)  alloc((size_t)NN*4);
  int*   esrc    = (int*)  alloc((size_t)ETOT*4);
  float* eattr   = (float*)alloc((size_t)ETOT*4);
  float* coef    = (float*)alloc(3*HEADS*4);
  float* wsd     = (float*)alloc(48*4);
  bf16*  wt      = (bf16*) alloc((size_t)2*FDIM*FDIM*2);  // layers 2,3 transposed bf16
  float* pf1     = (float*)alloc((size_t)8*1024*256*4);   // 8 MB
  float* pge     = (float*)alloc((size_t)8*NGRAPH*256*4); // 1 MB

  if (off > ws_size){
    k_sentinel<<<(out_size+255)/256, 256, 0, stream>>>(out, out_size);
    return;
  }

  // allow 64 KB dynamic LDS for the GEMM (CPU-side, idempotent, capture-safe)
  (void)hipFuncSetAttribute((const void*)gemm_mfma,
                            hipFuncAttributeMaxDynamicSharedMemorySize, 65536);

  // ---- CSR build + coef + layer1 ws/wd + wt transpose: one kernel ----
  k_csr<<<NGRAPH+4+1024, 512, 0, stream>>>(ei, ea, WEl[0], AEl[0], WEl[1], AEl[1], WEl[2], AEl[2],
                                           Wl[0], ASl[0], ADl[0], Wl[1], Wl[2],
                                           deg, row_ptr, la, esrc, eattr, coef, wsd, wt);

  // ---- layer 1: fully fused in x-space ----
  k_gat1<<<NN/4, 256, 0, stream>>>(x, Wl[0], wsd, coef, row_ptr, deg, esrc, eattr, Bl[0], h);

  // ---- layers 2,3: GEMM (+ fused logits) then gather-aggregate ----
  for (int l=1;l<3;l++){
    gemm_mfma<<<512, 512, 65536, stream>>>(h, wt + (size_t)(l-1)*FDIM*FDIM,
                                           ASl[l], ADl[l], xs, als, ald, NN, FDIM, FDIM);
    k_gat<<<NN/4, 256, 0, stream>>>(xs, als, ald, coef + l*HEADS, row_ptr, deg, esrc, eattr, la, Bl[l], h);
  }

  // ---- head ----
  k_head1<<<NGRAPH*8, 256, 0, stream>>>(h, FC1W, pf1, pge);
  k_fc2 <<<NGRAPH, 256, 0, stream>>>(pf1, pge, FC1B, FC2W, FC2B, out);
}

// Round 18
// 229.968 us; speedup vs baseline: 2.4990x; 2.4990x over previous
//
#include <hip/hip_runtime.h>
#include <hip/hip_bf16.h>
#include <math.h>

#define NGRAPH 128
#define NPG_   512
#define NN     (NGRAPH*NPG_)     // 65536 nodes
#define EPG    504
#define ETOT   (NGRAPH*EPG)      // 64512 real edges
#define HEADS  8
#define FDIM   512
#define NEG    0.2f

typedef __hip_bfloat16 bf16;
typedef __attribute__((ext_vector_type(8))) short short8;   // 8 bf16 = 4 VGPR
typedef __attribute__((ext_vector_type(4))) float f32x4;

static __device__ __forceinline__ float bf(short s){
  union { unsigned u; float f; } c; c.u = ((unsigned)(unsigned short)s) << 16; return c.f;
}
static __device__ __forceinline__ short fbf(float v){
  bf16 b = __float2bfloat16(v); return *(short*)&b;
}

static __device__ __forceinline__ void gload16(void* lds, const void* g){
  __builtin_amdgcn_global_load_lds((const __attribute__((address_space(1))) void*)g,
                                   (__attribute__((address_space(3))) void*)lds, 16, 0, 0);
}

// ---------------- workspace guard ----------------
__global__ void k_sentinel(float* out, int n){
  int i = blockIdx.x*blockDim.x + threadIdx.x;
  if (i < n) out[i] = 12345.0f;
}

// ---- one kernel: CSR build (0..127) + coef (128..130) + layer1 ws/wd (131) + wt (132..1155) ----
__global__ __launch_bounds__(512) void k_csr(const int* __restrict__ ei, const float* __restrict__ ea,
                                             const float* __restrict__ We0, const float* __restrict__ ae0,
                                             const float* __restrict__ We1, const float* __restrict__ ae1,
                                             const float* __restrict__ We2, const float* __restrict__ ae2,
                                             const float* __restrict__ W1,
                                             const float* __restrict__ as1, const float* __restrict__ ad1,
                                             const float* __restrict__ Wl2, const float* __restrict__ Wl3,
                                             int* __restrict__ deg_g, int* __restrict__ row_ptr,
                                             float* __restrict__ la,
                                             int* __restrict__ esrc, float* __restrict__ eattr,
                                             float* __restrict__ coef, float* __restrict__ wsd,
                                             bf16* __restrict__ wt){
  int b = blockIdx.x;
  int t = threadIdx.x;
  if (b >= NGRAPH){
    if (b < NGRAPH+3){                  // coef[l][h] = sum_c We[h*64+c]*ae[h*64+c]
      int l = b - NGRAPH;
      const float* We = l==0 ? We0 : (l==1 ? We1 : We2);
      const float* ae = l==0 ? ae0 : (l==1 ? ae1 : ae2);
      float v = We[t]*ae[t];
      #pragma unroll
      for (int o=32;o>0;o>>=1) v += __shfl_down(v, o);
      if ((t & 63) == 0) coef[l*HEADS + (t>>6)] = v;
      return;
    }
    if (b == NGRAPH+3){
      // layer-1 x-space attention vectors: ws[h][k] = sum_c W1[k*512+h*64+c]*as1[h*64+c]
      float as_v = as1[t], ad_v = ad1[t];
      float v[6] = { W1[t]*as_v, W1[512+t]*as_v, W1[1024+t]*as_v,
                     W1[t]*ad_v, W1[512+t]*ad_v, W1[1024+t]*ad_v };
      #pragma unroll
      for (int o=32;o>0;o>>=1){
        #pragma unroll
        for (int q=0;q<6;q++) v[q] += __shfl_down(v[q], o);
      }
      if ((t & 63) == 0){
        int w = t >> 6;
        wsd[w*3+0]    = v[0]; wsd[w*3+1]    = v[1]; wsd[w*3+2]    = v[2];
        wsd[24+w*3+0] = v[3]; wsd[24+w*3+1] = v[4]; wsd[24+w*3+2] = v[5];
      }
      return;
    }
    // wt blocks: transpose W2/W3 to bf16 [n][k]
    int idx = (b - (NGRAPH+4))*512 + t;          // [0, 2*FDIM*FDIM)
    int l = idx >> 18;
    int r = idx & (FDIM*FDIM-1);
    int n = r >> 9, k = r & 511;
    const float* W = l ? Wl3 : Wl2;
    wt[idx] = __float2bfloat16(W[k*FDIM + n]);
    return;
  }
  __shared__ int   dg[512];
  __shared__ float ss[512];
  __shared__ int   scan[512];
  __shared__ int   cur[512];
  dg[t] = 0; ss[t] = 0.f;
  __syncthreads();
  int src=0, dst=0; float at=0.f;
  if (t < EPG){
    src = ei[(b*EPG+t)*2];
    dst = ei[(b*EPG+t)*2+1];
    at  = ea[b*EPG+t];
    atomicAdd(&dg[dst], 1);
    atomicAdd(&ss[dst], at);
  }
  __syncthreads();
  int d = dg[t];
  scan[t] = d;
  __syncthreads();
  for (int o=1;o<512;o<<=1){
    int v2 = (t>=o) ? scan[t-o] : 0;
    __syncthreads();
    scan[t] += v2;
    __syncthreads();
  }
  int excl = scan[t] - d;
  int n = b*NPG_ + t;
  row_ptr[n] = b*EPG + excl;
  deg_g[n]   = d;
  la[n]      = ss[t] / fmaxf((float)d, 1.f);
  cur[t] = excl;
  __syncthreads();
  if (t < EPG){
    int slot = atomicAdd(&cur[dst], 1);
    int p = b*EPG + slot;
    esrc[p]  = b*NPG_ + src;
    eattr[p] = at;
  }
}

// ---------------- fully-fused layer 1 in x-space (3-dim) ----------------
__global__ __launch_bounds__(256) void k_gat1(const float* __restrict__ x,
                                              const float* __restrict__ W,
                                              const float* __restrict__ wsd,
                                              const float* __restrict__ coef,
                                              const int* __restrict__ row_ptr,
                                              const int* __restrict__ deg,
                                              const int* __restrict__ esrc,
                                              const float* __restrict__ eattr,
                                              const float* __restrict__ bias,
                                              bf16* __restrict__ h){
  int nwg = gridDim.x;                   // 16384, %8 == 0
  int cpx = nwg >> 3;
  int bid = blockIdx.x;
  int swz = (bid & 7)*cpx + (bid >> 3);
  int n = swz*4 + (threadIdx.x >> 6);
  int lane = threadIdx.x & 63;
  int hh = lane >> 3;
  int f0 = lane << 3;

  float ws0 = wsd[hh*3+0],    ws1 = wsd[hh*3+1],    ws2 = wsd[hh*3+2];
  float wd0 = wsd[24+hh*3+0], wd1 = wsd[24+hh*3+1], wd2 = wsd[24+hh*3+2];
  float ch = coef[hh];

  const float* xr = x + n*3;
  float aldn = xr[0]*wd0 + xr[1]*wd1 + xr[2]*wd2;

  int row = row_ptr[n], d = deg[n];
  float m = -1e30f, ssum = 0.f;
  float a0 = 0.f, a1 = 0.f, a2 = 0.f;
  for (int i=0;i<d;i++){
    int s = esrc[row+i]; float at = eattr[row+i];
    const float* xsr = x + s*3;
    float y0 = xsr[0], y1 = xsr[1], y2 = xsr[2];
    float raw = y0*ws0 + y1*ws1 + y2*ws2 + aldn + at*ch;
    raw = raw > 0.f ? raw : NEG*raw;
    float mn = fmaxf(m, raw);
    float sc = __expf(m - mn);
    float p  = __expf(raw - mn);
    ssum = ssum*sc + p;
    a0 = a0*sc + p*y0;
    a1 = a1*sc + p*y1;
    a2 = a2*sc + p*y2;
    m = mn;
  }
  float inv = 1.f / fmaxf(ssum, 1e-16f);
  a0 *= inv; a1 *= inv; a2 *= inv;

  float w0[8], w1[8], w2[8], b8[8];
  #pragma unroll
  for (int j=0;j<8;j+=4){
    *(float4*)&w0[j] = *(const float4*)&W[f0+j];
    *(float4*)&w1[j] = *(const float4*)&W[FDIM+f0+j];
    *(float4*)&w2[j] = *(const float4*)&W[2*FDIM+f0+j];
    *(float4*)&b8[j] = *(const float4*)&bias[f0+j];
  }
  short8 r;
  #pragma unroll
  for (int j=0;j<8;j++){
    float o = a0*w0[j] + a1*w1[j] + a2*w2[j] + b8[j];
    r[j] = fbf(o > 0.f ? o : 0.f);
  }
  ((short8*)(h + (size_t)n*FDIM))[lane] = r;
}

// ---------------- fused GAT: single-pass online softmax; wave per node ----------------
__global__ __launch_bounds__(256) void k_gat(const bf16* __restrict__ xs,
                                             const float* __restrict__ als,
                                             const float* __restrict__ ald,
                                             const float* __restrict__ coef,
                                             const int* __restrict__ row_ptr,
                                             const int* __restrict__ deg,
                                             const int* __restrict__ esrc,
                                             const float* __restrict__ eattr,
                                             const float* __restrict__ la,
                                             const float* __restrict__ bias,
                                             bf16* __restrict__ h){
  int nwg = gridDim.x;                   // 16384, %8 == 0
  int cpx = nwg >> 3;
  int bid = blockIdx.x;
  int swz = (bid & 7)*cpx + (bid >> 3);
  int n = swz*4 + (threadIdx.x >> 6);
  int lane = threadIdx.x & 63;
  int hh = lane >> 3;                    // head of my 8 features
  int row = row_ptr[n], d = deg[n];
  int tot = d + 1;                       // self loop
  float aldn = ald[n*HEADS+hh];
  float ch = coef[hh];
  float lan = la[n];

  float m = -1e30f, ssum = 0.f;
  float acc[8] = {};
  for (int i=0;i<tot;i++){
    int s; float at;
    if (i<d){ s = esrc[row+i]; at = eattr[row+i]; }
    else    { s = n;           at = lan; }
    float raw = als[s*HEADS+hh] + aldn + at*ch;
    raw = raw > 0.f ? raw : NEG*raw;
    float mn = fmaxf(m, raw);
    float scale = __expf(m - mn);        // 1 if max unchanged; 0 on first iter
    float p = __expf(raw - mn);
    ssum = ssum*scale + p;
    short8 v = ((const short8*)(xs + (size_t)s*FDIM))[lane];
    #pragma unroll
    for (int j=0;j<8;j++) acc[j] = acc[j]*scale + p*bf(v[j]);
    m = mn;
  }
  float inv = 1.f / fmaxf(ssum, 1e-16f);
  const float4* b4 = (const float4*)bias;
  float4 ba = b4[lane*2], bb = b4[lane*2+1];
  float bias8[8] = {ba.x,ba.y,ba.z,ba.w,bb.x,bb.y,bb.z,bb.w};
  short8 r;
  #pragma unroll
  for (int j=0;j<8;j++){
    float o = acc[j]*inv + bias8[j];
    r[j] = fbf(o > 0.f ? o : 0.f);
  }
  ((short8*)(h + (size_t)n*FDIM))[lane] = r;
}

// ------- 256x256 MFMA GEMM (r16-proven): BK=64, 2-slot 128KB, counted vmcnt(8),
// fused attn logits. launch_bounds(512,2): 256-VGPR budget -- (512,4) spilled acc
// to scratch (r17: VGPR 64, 735MB scratch writes). Do NOT raise min-waves here.
__global__ __launch_bounds__(512, 2) void gemm_mfma(const bf16* __restrict__ A,
                                                    const bf16* __restrict__ Wt,
                                                    const float* __restrict__ a_s,
                                                    const float* __restrict__ a_d,
                                                    bf16* __restrict__ C,
                                                    float* __restrict__ als,
                                                    float* __restrict__ ald,
                                                    int M, int N, int K){
  extern __shared__ short smem[];        // 2 slots * 32768 shorts (A 16384 + B 16384)
  int bid = blockIdx.x;
  int wk = ((bid & 7) << 6) | (bid >> 3);    // XCD chunk swizzle (512 = 8*64)
  const int bm = (wk >> 1)*256, bn = (wk & 1)*256;   // N-minor: A-panel L2 reuse
  const int tid = threadIdx.x;
  const int lane = tid & 63;
  const int w = tid >> 6;                // 0..7
  const int wm = (w >> 2)*128;           // 0,128
  const int wn = (w & 3)*64;             // 0,64,128,192
  const int lr = lane & 15;
  const int lk = lane >> 4;

  f32x4 acc[8][4] = {};
  const int nt = K >> 6;                 // 8 K-tiles of 64

  auto STAGE = [&](int s, int t){
    short* Al = smem + s*32768;
    short* Bl = smem + s*32768 + 16384;
    int k0 = t << 6;
    #pragma unroll
    for (int ph=0; ph<4; ++ph){
      int i = ph*512 + tid;              // 0..2047 granules (256 rows x 8)
      int r = i >> 3, g = i & 7;
      int gs = g ^ (r & 7);
      gload16(&Al[i*8], A  + (size_t)(bm+r)*K + k0 + gs*8);
      gload16(&Bl[i*8], Wt + (size_t)(bn+r)*K + k0 + gs*8);
    }
  };

  STAGE(0, 0);
  for (int t = 0; t < nt; ++t){
    int s = t & 1;
    if (t+1 < nt){
      STAGE(s^1, t+1);
      asm volatile("s_waitcnt vmcnt(8)" ::: "memory");   // tile t landed; t+1 in flight
    } else {
      asm volatile("s_waitcnt vmcnt(0)" ::: "memory");   // last tile: drain
    }
    __builtin_amdgcn_s_barrier();
    const short* Al = smem + s*32768;
    const short* Bl = smem + s*32768 + 16384;
    __builtin_amdgcn_s_setprio(1);
    #pragma unroll
    for (int kk=0; kk<2; ++kk){
      short8 af[8], bfr[4];
      #pragma unroll
      for (int mi=0; mi<8; ++mi){
        int row = wm + mi*16 + lr;
        af[mi] = *(const short8*)&Al[row*64 + (((kk<<2)|lk) ^ (row&7))*8];
      }
      #pragma unroll
      for (int ni=0; ni<4; ++ni){
        int row = wn + ni*16 + lr;
        bfr[ni] = *(const short8*)&Bl[row*64 + (((kk<<2)|lk) ^ (row&7))*8];
      }
      #pragma unroll
      for (int mi=0; mi<8; ++mi)
        #pragma unroll
        for (int ni=0; ni<4; ++ni)
          acc[mi][ni] = __builtin_amdgcn_mfma_f32_16x16x32_bf16(af[mi], bfr[ni], acc[mi][ni], 0,0,0);
    }
    __builtin_amdgcn_s_setprio(0);
    __builtin_amdgcn_s_barrier();        // all frags consumed -> restage-safe next iter
  }

  // fused attention logits from hot f32 acc: this wave's 64 cols = one head
  int hh = (bn + wn) >> 6;
  float as_c[4], ad_c[4];
  #pragma unroll
  for (int ni=0; ni<4; ++ni){
    int c = bn + wn + ni*16 + lr;       // == hh*64 + ni*16 + lr
    as_c[ni] = a_s[c & 511];
    ad_c[ni] = a_d[c & 511];
  }
  #pragma unroll
  for (int mi=0; mi<8; ++mi)
    #pragma unroll
    for (int r=0; r<4; ++r){
      float s = acc[mi][0][r]*as_c[0] + acc[mi][1][r]*as_c[1]
              + acc[mi][2][r]*as_c[2] + acc[mi][3][r]*as_c[3];
      float d = acc[mi][0][r]*ad_c[0] + acc[mi][1][r]*ad_c[1]
              + acc[mi][2][r]*ad_c[2] + acc[mi][3][r]*ad_c[3];
      #pragma unroll
      for (int o=1;o<16;o<<=1){ s += __shfl_xor(s, o); d += __shfl_xor(d, o); }
      if (lr == 0){
        int rowg = bm + wm + mi*16 + lk*4 + r;
        als[rowg*HEADS+hh] = s;
        ald[rowg*HEADS+hh] = d;
      }
    }

  // C write: col = lane&15, row = (lane>>4)*4 + reg   (m89 layout)
  #pragma unroll
  for (int mi=0; mi<8; ++mi)
    #pragma unroll
    for (int ni=0; ni<4; ++ni){
      int col = bn + wn + ni*16 + lr;
      #pragma unroll
      for (int r=0; r<4; ++r){
        int rowg = bm + wm + mi*16 + lk*4 + r;
        C[(size_t)rowg*N + col] = __float2bfloat16(acc[mi][ni][r]);
      }
    }
}

// ---- head part 1: FC1 partials, K-split 8x; graph-mean chunk computed in-kernel ----
__global__ __launch_bounds__(256) void k_head1(const bf16* __restrict__ h,
                                               const float* __restrict__ fc1w,
                                               float* __restrict__ pf1,
                                               float* __restrict__ pge){
  __shared__ float geP[4][64];
  __shared__ float ge[64];
  __shared__ float ag[8][64];
  int blk = blockIdx.x;                 // g*8 + q
  int g = blk >> 3, q = blk & 7;
  int t = threadIdx.x;
  int k0 = q*64;

  // graph-mean partial for this 64-chunk: 4 row-groups x 128 rows, coalesced 128B rows
  {
    int cg = t & 63, rg = t >> 6;
    const bf16* p = h + ((size_t)(g*NPG_ + rg*128))*FDIM + k0 + cg;
    float s = 0.f;
    #pragma unroll 8
    for (int r=0;r<128;r++) s += bf(*(const short*)(p + (size_t)r*FDIM));
    geP[rg][cg] = s;
  }
  // agent rows (first 8 nodes of graph): 64 units = 8 rows x 8 short8
  if (t < 64){
    int r = t >> 3, c8 = t & 7;
    short8 v = ((const short8*)(h + ((size_t)(g*NPG_ + r))*FDIM + k0))[c8];
    #pragma unroll
    for (int j=0;j<8;j++) ag[r][c8*8+j] = bf(v[j]);
  }
  __syncthreads();
  if (t < 64) ge[t] = (geP[0][t]+geP[1][t]+geP[2][t]+geP[3][t]) * (1.f/NPG_);
  __syncthreads();

  float acc[8] = {};
  float gacc = 0.f;
  for (int kk=0; kk<64; kk++){
    float wa = fc1w[(size_t)(k0+kk)*256 + t];
    float wg = fc1w[(size_t)(FDIM+k0+kk)*256 + t];
    #pragma unroll
    for (int r=0;r<8;r++) acc[r] += ag[r][kk]*wa;
    gacc += ge[kk]*wg;
  }
  #pragma unroll
  for (int r=0;r<8;r++) pf1[((size_t)q*1024 + g*8 + r)*256 + t] = acc[r];
  pge[((size_t)q*NGRAPH + g)*256 + t] = gacc;
}

// ---------------- head part 2: reduce partials + bias + ReLU + FC2 ----------------
__global__ __launch_bounds__(256) void k_fc2(const float* __restrict__ pf1,
                                             const float* __restrict__ pge,
                                             const float* __restrict__ fc1b,
                                             const float* __restrict__ fc2w,
                                             const float* __restrict__ fc2b,
                                             float* __restrict__ out){
  __shared__ float f1[8][256];
  int g = blockIdx.x, t = threadIdx.x;
  float ges = 0.f;
  #pragma unroll
  for (int q=0;q<8;q++) ges += pge[((size_t)q*NGRAPH + g)*256 + t];
  float b = fc1b[t] + ges;
  #pragma unroll
  for (int r=0;r<8;r++){
    float s = 0.f;
    #pragma unroll
    for (int q=0;q<8;q++) s += pf1[((size_t)q*1024 + g*8 + r)*256 + t];
    f1[r][t] = fmaxf(s + b, 0.f);
  }
  __syncthreads();
  if (t < 128){
    int r = t >> 4, o = (t >> 3) & 1, l = t & 7;
    float s = 0.f;
    for (int k = l; k < 256; k += 8) s += f1[r][k] * fc2w[k*2+o];
    #pragma unroll
    for (int off=4; off; off>>=1) s += __shfl_down(s, off);
    if (l == 0) out[(g*8 + r)*2 + o] = s + fc2b[o];
  }
}

extern "C" void kernel_launch(void* const* d_in, const int* in_sizes, int n_in,
                              void* d_out, int out_size, void* d_ws, size_t ws_size,
                              hipStream_t stream)
{
  const float* x    = (const float*)d_in[0];
  const int*   ei   = (const int*)  d_in[1];
  const float* ea   = (const float*)d_in[2];
  const float* Wl[3]  = {(const float*)d_in[3],  (const float*)d_in[9],  (const float*)d_in[15]};
  const float* Bl[3]  = {(const float*)d_in[4],  (const float*)d_in[10], (const float*)d_in[16]};
  const float* ASl[3] = {(const float*)d_in[5],  (const float*)d_in[11], (const float*)d_in[17]};
  const float* ADl[3] = {(const float*)d_in[6],  (const float*)d_in[12], (const float*)d_in[18]};
  const float* WEl[3] = {(const float*)d_in[7],  (const float*)d_in[13], (const float*)d_in[19]};
  const float* AEl[3] = {(const float*)d_in[8],  (const float*)d_in[14], (const float*)d_in[20]};
  const float* FC1W = (const float*)d_in[21];
  const float* FC1B = (const float*)d_in[22];
  const float* FC2W = (const float*)d_in[23];
  const float* FC2B = (const float*)d_in[24];
  float* out = (float*)d_out;
  (void)in_sizes; (void)n_in;

  char* ws = (char*)d_ws;
  size_t off = 0;
  auto alloc = [&](size_t bytes)->char*{
    char* p = ws + off;
    off = (off + bytes + 255) & ~(size_t)255;
    return p;
  };
  bf16*  h       = (bf16*) alloc((size_t)NN*FDIM*2);    // 64 MB
  bf16*  xs      = (bf16*) alloc((size_t)NN*FDIM*2);    // 64 MB
  float* als     = (float*)alloc((size_t)NN*HEADS*4);   // 2 MB
  float* ald     = (float*)alloc((size_t)NN*HEADS*4);   // 2 MB
  float* la      = (float*)alloc((size_t)NN*4);
  int*   deg     = (int*)  alloc((size_t)NN*4);
  int*   row_ptr = (int*)  alloc((size_t)NN*4);
  int*   esrc    = (int*)  alloc((size_t)ETOT*4);
  float* eattr   = (float*)alloc((size_t)ETOT*4);
  float* coef    = (float*)alloc(3*HEADS*4);
  float* wsd     = (float*)alloc(48*4);
  bf16*  wt      = (bf16*) alloc((size_t)2*FDIM*FDIM*2);  // layers 2,3 transposed bf16
  float* pf1     = (float*)alloc((size_t)8*1024*256*4);   // 8 MB
  float* pge     = (float*)alloc((size_t)8*NGRAPH*256*4); // 1 MB

  if (off > ws_size){
    k_sentinel<<<(out_size+255)/256, 256, 0, stream>>>(out, out_size);
    return;
  }

  // allow 128 KB dynamic LDS for the GEMM (CPU-side, idempotent, capture-safe)
  (void)hipFuncSetAttribute((const void*)gemm_mfma,
                            hipFuncAttributeMaxDynamicSharedMemorySize, 131072);

  // ---- CSR build + coef + layer1 ws/wd + wt transpose: one kernel ----
  k_csr<<<NGRAPH+4+1024, 512, 0, stream>>>(ei, ea, WEl[0], AEl[0], WEl[1], AEl[1], WEl[2], AEl[2],
                                           Wl[0], ASl[0], ADl[0], Wl[1], Wl[2],
                                           deg, row_ptr, la, esrc, eattr, coef, wsd, wt);

  // ---- layer 1: fully fused in x-space ----
  k_gat1<<<NN/4, 256, 0, stream>>>(x, Wl[0], wsd, coef, row_ptr, deg, esrc, eattr, Bl[0], h);

  // ---- layers 2,3: GEMM (+ fused logits) then gather-aggregate ----
  for (int l=1;l<3;l++){
    gemm_mfma<<<512, 512, 131072, stream>>>(h, wt + (size_t)(l-1)*FDIM*FDIM,
                                            ASl[l], ADl[l], xs, als, ald, NN, FDIM, FDIM);
    k_gat<<<NN/4, 256, 0, stream>>>(xs, als, ald, coef + l*HEADS, row_ptr, deg, esrc, eattr, la, Bl[l], h);
  }

  // ---- head ----
  k_head1<<<NGRAPH*8, 256, 0, stream>>>(h, FC1W, pf1, pge);
  k_fc2 <<<NGRAPH, 256, 0, stream>>>(pf1, pge, FC1B, FC2W, FC2B, out);
}